// Round 2
// baseline (2113.239 us; speedup 1.0000x reference)
//
#include <hip/hip_runtime.h>
#include <hip/hip_bf16.h>

#define SEQ    576
#define DIM    640
#define HEADS  8
#define HD     80          // DIM / HEADS
#define NF     4
#define NB     12          // 3 * NF
#define M_TOT  (NB * SEQ)  // 6912

// ---------------------------------------------------------------------------
// QKV projection:  Y[m,e] = sum_d X[m,d] * W[e,d]   (all fp32)
// 64x64 tile, block 256 (16x16 threads, 4x4 micro-tile), K-chunks of 16.
// grid = (M/64, N/64, 3)  z selects (Wq->Q, Wk->K, Wv->V)
// ---------------------------------------------------------------------------
__global__ __launch_bounds__(256) void qkv_gemm_kernel(
    const float* __restrict__ X,
    const float* __restrict__ Wq,
    const float* __restrict__ Wk,
    const float* __restrict__ Wv,
    float* __restrict__ Q, float* __restrict__ K, float* __restrict__ V)
{
    const int z = blockIdx.z;
    const float* __restrict__ W = (z == 0) ? Wq : ((z == 1) ? Wk : Wv);
    float* __restrict__ Y = (z == 0) ? Q : ((z == 1) ? K : V);

    const int m0 = blockIdx.x * 64;
    const int n0 = blockIdx.y * 64;

    // pad to 20 floats (80 B): keeps float4 alignment for [r][kk] reads
    __shared__ float As[64][20];
    __shared__ float Bs[64][20];

    const int t    = threadIdx.x;
    const int lrow = t >> 2;         // 0..63
    const int lcol = (t & 3) * 4;    // 0,4,8,12
    const int tx   = t & 15;
    const int ty   = t >> 4;

    float acc[4][4] = {};

    for (int k0 = 0; k0 < DIM; k0 += 16) {
        {
            const float4 fa = *(const float4*)(X + (size_t)(m0 + lrow) * DIM + k0 + lcol);
            As[lrow][lcol + 0] = fa.x;
            As[lrow][lcol + 1] = fa.y;
            As[lrow][lcol + 2] = fa.z;
            As[lrow][lcol + 3] = fa.w;
            const float4 fb = *(const float4*)(W + (size_t)(n0 + lrow) * DIM + k0 + lcol);
            Bs[lrow][lcol + 0] = fb.x;
            Bs[lrow][lcol + 1] = fb.y;
            Bs[lrow][lcol + 2] = fb.z;
            Bs[lrow][lcol + 3] = fb.w;
        }
        __syncthreads();
#pragma unroll
        for (int kk = 0; kk < 16; kk += 4) {
            float4 a[4], b[4];
#pragma unroll
            for (int i = 0; i < 4; ++i) a[i] = *(const float4*)&As[ty * 4 + i][kk];
#pragma unroll
            for (int j = 0; j < 4; ++j) b[j] = *(const float4*)&Bs[tx * 4 + j][kk];
#pragma unroll
            for (int i = 0; i < 4; ++i)
#pragma unroll
                for (int j = 0; j < 4; ++j)
                    acc[i][j] += a[i].x * b[j].x + a[i].y * b[j].y +
                                 a[i].z * b[j].z + a[i].w * b[j].w;
        }
        __syncthreads();
    }

#pragma unroll
    for (int i = 0; i < 4; ++i) {
        float4 r4 = make_float4(acc[i][0], acc[i][1], acc[i][2], acc[i][3]);
        *(float4*)(Y + (size_t)(m0 + ty * 4 + i) * DIM + n0 + tx * 4) = r4;
    }
}

// ---------------------------------------------------------------------------
// Flash-style attention.
// grid = (SEQ/64, HEADS, NB), block 256 (4 waves).
// Frame f<4: self-attn over 576 keys of frame f.
// Frame 4..7 / 8..11: attend over 2304 keys of the frame-group (contiguous rows).
// Thread t: q-row = t&63, group g = t>>6 (wave-uniform).
//   S phase : computes S[q][g*16 + jj], jj=0..15  (K reads broadcast)
//   softmax : wave 0 (t<64), one row each, online m/l in registers
//   PV phase: thread owns output dims [g*20, g*20+20)  (V reads broadcast)
// ---------------------------------------------------------------------------
__global__ __launch_bounds__(256) void attn_kernel(
    const float* __restrict__ Q, const float* __restrict__ K,
    const float* __restrict__ V, float* __restrict__ O)
{
    const int qt = blockIdx.x;   // 0..8
    const int h  = blockIdx.y;   // 0..7
    const int f  = blockIdx.z;   // 0..11

    const int t = threadIdx.x;
    const int q = t & 63;
    const int g = t >> 6;        // wave id, uniform per wave
    const int d0 = g * 20;

    __shared__ float Ks[64][80];
    __shared__ float Vs[64][80];
    __shared__ float Ss[64][65];   // stride 65: (q+j)%32 banks -> 2-way (free)
    __shared__ float arow[64];
    __shared__ float lrow[64];

    const int kbase = (f < 4 ? f : (f < 8 ? 4 : 8)) * SEQ;
    const int nkt   = (f < 4) ? (SEQ / 64) : (NF * SEQ / 64);   // 9 : 36

    const int  qrow  = f * SEQ + qt * 64 + q;
    const float scale = 0.11180339887498949f;   // 1/sqrt(80)

    // Q row -> registers, pre-scaled
    float qreg[80];
    {
        const float* qp = Q + (size_t)qrow * DIM + h * HD;
#pragma unroll
        for (int d = 0; d < 80; d += 4) {
            float4 v4 = *(const float4*)(qp + d);
            qreg[d + 0] = v4.x * scale;
            qreg[d + 1] = v4.y * scale;
            qreg[d + 2] = v4.z * scale;
            qreg[d + 3] = v4.w * scale;
        }
    }

    float mrun = -INFINITY, lrun = 0.f;   // meaningful in threads t<64
    float oacc[20] = {};

    for (int kt = 0; kt < nkt; ++kt) {
        __syncthreads();   // previous iteration's Ss/Vs consumers done
        {
            const int r = t >> 2;           // 0..63
            const int c = (t & 3) * 20;     // 0,20,40,60
            const float* kp = K + (size_t)(kbase + kt * 64 + r) * DIM + h * HD + c;
            const float* vp = V + (size_t)(kbase + kt * 64 + r) * DIM + h * HD + c;
#pragma unroll
            for (int i = 0; i < 20; i += 4) {
                *(float4*)&Ks[r][c + i] = *(const float4*)(kp + i);
                *(float4*)&Vs[r][c + i] = *(const float4*)(vp + i);
            }
        }
        __syncthreads();

        // ---- S = (Q*scale) . K^T ----
#pragma unroll 1
        for (int jj = 0; jj < 16; ++jj) {
            const int j = g * 16 + jj;
            const float* kr = &Ks[j][0];
            float acc = 0.f;
#pragma unroll
            for (int d = 0; d < 80; d += 4) {
                float4 kv = *(const float4*)(kr + d);
                acc += qreg[d] * kv.x + qreg[d + 1] * kv.y +
                       qreg[d + 2] * kv.z + qreg[d + 3] * kv.w;
            }
            Ss[q][j] = acc;
        }
        __syncthreads();

        // ---- online softmax (wave 0) ----
        if (t < 64) {
            float mnew = mrun;
#pragma unroll 1
            for (int j = 0; j < 64; ++j) mnew = fmaxf(mnew, Ss[t][j]);
            const float alpha = __expf(mrun - mnew);   // first tile: exp(-inf)=0
            float s = 0.f;
#pragma unroll 1
            for (int j = 0; j < 64; ++j) {
                float p = __expf(Ss[t][j] - mnew);
                Ss[t][j] = p;
                s += p;
            }
            lrun = lrun * alpha + s;
            mrun = mnew;
            arow[t] = alpha;
        }
        __syncthreads();

        // ---- O = alpha*O + P.V ----
        const float alpha = arow[q];
#pragma unroll
        for (int i = 0; i < 20; ++i) oacc[i] *= alpha;
#pragma unroll 1
        for (int j = 0; j < 64; ++j) {
            const float p = Ss[q][j];
            const float* vr = &Vs[j][d0];
#pragma unroll
            for (int i = 0; i < 20; i += 4) {
                float4 vv = *(const float4*)(vr + i);
                oacc[i + 0] += p * vv.x;
                oacc[i + 1] += p * vv.y;
                oacc[i + 2] += p * vv.z;
                oacc[i + 3] += p * vv.w;
            }
        }
    }

    if (t < 64) lrow[t] = lrun;
    __syncthreads();

    const float inv_l = 1.f / lrow[q];
    float* op = O + (size_t)qrow * DIM + h * HD + d0;
#pragma unroll
    for (int i = 0; i < 20; i += 4) {
        float4 r4 = make_float4(oacc[i] * inv_l, oacc[i + 1] * inv_l,
                                oacc[i + 2] * inv_l, oacc[i + 3] * inv_l);
        *(float4*)(op + i) = r4;
    }
}

// ---------------------------------------------------------------------------
// Output projection: out[m,e] = sum_d A[m,d]*Wo[e,d] + bo[e]   (all fp32)
// ---------------------------------------------------------------------------
__global__ __launch_bounds__(256) void oproj_gemm_kernel(
    const float* __restrict__ A,
    const float* __restrict__ Wo,
    const float* __restrict__ bo,
    float* __restrict__ out)
{
    const int m0 = blockIdx.x * 64;
    const int n0 = blockIdx.y * 64;

    __shared__ float As[64][20];
    __shared__ float Bs[64][20];

    const int t    = threadIdx.x;
    const int lrow = t >> 2;
    const int lcol = (t & 3) * 4;
    const int tx   = t & 15;
    const int ty   = t >> 4;

    float acc[4][4] = {};

    for (int k0 = 0; k0 < DIM; k0 += 16) {
        {
            const float4 fa = *(const float4*)(A + (size_t)(m0 + lrow) * DIM + k0 + lcol);
            As[lrow][lcol + 0] = fa.x;
            As[lrow][lcol + 1] = fa.y;
            As[lrow][lcol + 2] = fa.z;
            As[lrow][lcol + 3] = fa.w;
            const float4 fb = *(const float4*)(Wo + (size_t)(n0 + lrow) * DIM + k0 + lcol);
            Bs[lrow][lcol + 0] = fb.x;
            Bs[lrow][lcol + 1] = fb.y;
            Bs[lrow][lcol + 2] = fb.z;
            Bs[lrow][lcol + 3] = fb.w;
        }
        __syncthreads();
#pragma unroll
        for (int kk = 0; kk < 16; kk += 4) {
            float4 a[4], b[4];
#pragma unroll
            for (int i = 0; i < 4; ++i) a[i] = *(const float4*)&As[ty * 4 + i][kk];
#pragma unroll
            for (int j = 0; j < 4; ++j) b[j] = *(const float4*)&Bs[tx * 4 + j][kk];
#pragma unroll
            for (int i = 0; i < 4; ++i)
#pragma unroll
                for (int j = 0; j < 4; ++j)
                    acc[i][j] += a[i].x * b[j].x + a[i].y * b[j].y +
                                 a[i].z * b[j].z + a[i].w * b[j].w;
        }
        __syncthreads();
    }

#pragma unroll
    for (int i = 0; i < 4; ++i) {
        float4 r4;
        r4.x = acc[i][0] + bo[n0 + tx * 4 + 0];
        r4.y = acc[i][1] + bo[n0 + tx * 4 + 1];
        r4.z = acc[i][2] + bo[n0 + tx * 4 + 2];
        r4.w = acc[i][3] + bo[n0 + tx * 4 + 3];
        *(float4*)(out + (size_t)(m0 + ty * 4 + i) * DIM + n0 + tx * 4) = r4;
    }
}

// ---------------------------------------------------------------------------
extern "C" void kernel_launch(void* const* d_in, const int* in_sizes, int n_in,
                              void* d_out, int out_size, void* d_ws, size_t ws_size,
                              hipStream_t stream)
{
    const float* x  = (const float*)d_in[0];
    const float* Wq = (const float*)d_in[1];
    const float* Wk = (const float*)d_in[2];
    const float* Wv = (const float*)d_in[3];
    const float* Wo = (const float*)d_in[4];
    const float* bo = (const float*)d_in[5];
    float* out = (float*)d_out;

    float* qb = (float*)d_ws;                    // [6912][640] fp32
    float* kb = qb + (size_t)M_TOT * DIM;
    float* vb = kb + (size_t)M_TOT * DIM;
    float* ab = vb + (size_t)M_TOT * DIM;        // attention output, pre-proj

    dim3 g1(M_TOT / 64, DIM / 64, 3);
    qkv_gemm_kernel<<<g1, 256, 0, stream>>>(x, Wq, Wk, Wv, qb, kb, vb);

    dim3 g2(SEQ / 64, HEADS, NB);
    attn_kernel<<<g2, 256, 0, stream>>>(qb, kb, vb, ab);

    dim3 g3(M_TOT / 64, DIM / 64);
    oproj_gemm_kernel<<<g3, 256, 0, stream>>>(ab, Wo, bo, out);
}

// Round 3
// 384.165 us; speedup vs baseline: 5.5009x; 5.5009x over previous
//
#include <hip/hip_runtime.h>
#include <hip/hip_bf16.h>

#define SEQ    576
#define DIM    640
#define HEADS  8
#define HD     80          // DIM / HEADS
#define NF     4
#define NB     12          // 3 * NF
#define M_TOT  (NB * SEQ)  // 6912

typedef __attribute__((ext_vector_type(8))) short          bf16x8;
typedef __attribute__((ext_vector_type(4))) float          f32x4;
typedef __attribute__((ext_vector_type(8))) unsigned short u16x8;
typedef __attribute__((ext_vector_type(4))) unsigned short u16x4;

__device__ __forceinline__ unsigned short f2bf(float x) {
    unsigned u = __float_as_uint(x);
    u += 0x7fffu + ((u >> 16) & 1u);
    return (unsigned short)(u >> 16);
}
__device__ __forceinline__ float bf2f(unsigned short h) {
    return __uint_as_float((unsigned)h << 16);
}
__device__ __forceinline__ f32x4 mfma16(bf16x8 a, bf16x8 b, f32x4 c) {
    return __builtin_amdgcn_mfma_f32_16x16x32_bf16(a, b, c, 0, 0, 0);
}

// ---------------------------------------------------------------------------
// GEMM body:  C[m,n] = sum_k A[m,k] * B[n,k]  (+bias[n])   A:MxK, B:NxK fp32
// bf16 hi/lo x3 MFMA (hh + hl + lh) == fp32-accurate.
// block 256 (4 waves); tile 128(M) x 64(N); BK=32.
// ---------------------------------------------------------------------------
__device__ __forceinline__ void gemm_body(
    const float* __restrict__ A, const float* __restrict__ B,
    const float* __restrict__ bias, float* __restrict__ C,
    int m0, int n0)
{
    __shared__ unsigned short Ah[128 * 40], Al[128 * 40];
    __shared__ unsigned short Bh[64 * 40],  Bl[64 * 40];

    const int t    = threadIdx.x;
    const int w    = t >> 6;
    const int lane = t & 63;
    const int quad = lane >> 4;
    const int ln   = lane & 15;

    f32x4 acc[2][4];
#pragma unroll
    for (int mi = 0; mi < 2; ++mi)
#pragma unroll
        for (int nt = 0; nt < 4; ++nt)
#pragma unroll
            for (int e = 0; e < 4; ++e) acc[mi][nt][e] = 0.f;

    for (int k0 = 0; k0 < DIM; k0 += 32) {
        __syncthreads();
        // stage A: 128x32, thread: row t>>1, cols (t&1)*16 + [0,16)
        {
            const int r  = t >> 1;
            const int c0 = (t & 1) * 16;
            const float* ap = A + (size_t)(m0 + r) * DIM + k0 + c0;
#pragma unroll
            for (int i = 0; i < 16; i += 8) {
                float4 a4 = *(const float4*)(ap + i);
                float4 b4 = *(const float4*)(ap + i + 4);
                float vv[8] = {a4.x, a4.y, a4.z, a4.w, b4.x, b4.y, b4.z, b4.w};
                union { unsigned short u[8]; u16x8 v; } ph, pl;
#pragma unroll
                for (int j = 0; j < 8; ++j) {
                    unsigned short hh = f2bf(vv[j]);
                    ph.u[j] = hh;
                    pl.u[j] = f2bf(vv[j] - bf2f(hh));
                }
                *(u16x8*)&Ah[r * 40 + c0 + i] = ph.v;
                *(u16x8*)&Al[r * 40 + c0 + i] = pl.v;
            }
        }
        // stage B: 64x32, thread: row t>>2, cols (t&3)*8 + [0,8)
        {
            const int r  = t >> 2;
            const int c0 = (t & 3) * 8;
            const float* bp = B + (size_t)(n0 + r) * DIM + k0 + c0;
            float4 a4 = *(const float4*)(bp);
            float4 b4 = *(const float4*)(bp + 4);
            float vv[8] = {a4.x, a4.y, a4.z, a4.w, b4.x, b4.y, b4.z, b4.w};
            union { unsigned short u[8]; u16x8 v; } ph, pl;
#pragma unroll
            for (int j = 0; j < 8; ++j) {
                unsigned short hh = f2bf(vv[j]);
                ph.u[j] = hh;
                pl.u[j] = f2bf(vv[j] - bf2f(hh));
            }
            *(u16x8*)&Bh[r * 40 + c0] = ph.v;
            *(u16x8*)&Bl[r * 40 + c0] = pl.v;
        }
        __syncthreads();

        bf16x8 ah[2], al[2];
#pragma unroll
        for (int mi = 0; mi < 2; ++mi) {
            const int off = (w * 32 + mi * 16 + ln) * 40 + quad * 8;
            ah[mi] = *(const bf16x8*)&Ah[off];
            al[mi] = *(const bf16x8*)&Al[off];
        }
#pragma unroll
        for (int nt = 0; nt < 4; ++nt) {
            const int off = (nt * 16 + ln) * 40 + quad * 8;
            bf16x8 bh = *(const bf16x8*)&Bh[off];
            bf16x8 bl = *(const bf16x8*)&Bl[off];
#pragma unroll
            for (int mi = 0; mi < 2; ++mi) {
                acc[mi][nt] = mfma16(ah[mi], bh, acc[mi][nt]);
                acc[mi][nt] = mfma16(ah[mi], bl, acc[mi][nt]);
                acc[mi][nt] = mfma16(al[mi], bh, acc[mi][nt]);
            }
        }
    }

#pragma unroll
    for (int mi = 0; mi < 2; ++mi)
#pragma unroll
        for (int r = 0; r < 4; ++r) {
            const int row = m0 + w * 32 + mi * 16 + quad * 4 + r;
#pragma unroll
            for (int nt = 0; nt < 4; ++nt) {
                const int col = n0 + nt * 16 + ln;
                float v = acc[mi][nt][r];
                if (bias) v += bias[col];
                C[(size_t)row * DIM + col] = v;
            }
        }
}

__global__ __launch_bounds__(256) void qkv_mfma_kernel(
    const float* __restrict__ X,
    const float* __restrict__ Wq, const float* __restrict__ Wk,
    const float* __restrict__ Wv,
    float* __restrict__ Qo, float* __restrict__ Ko, float* __restrict__ Vo)
{
    const int z = blockIdx.z;
    const float* W = (z == 0) ? Wq : ((z == 1) ? Wk : Wv);
    float* Y = (z == 0) ? Qo : ((z == 1) ? Ko : Vo);
    gemm_body(X, W, nullptr, Y, blockIdx.x * 128, blockIdx.y * 64);
}

__global__ __launch_bounds__(256) void oproj_mfma_kernel(
    const float* __restrict__ A, const float* __restrict__ Wo,
    const float* __restrict__ bo, float* __restrict__ out)
{
    gemm_body(A, Wo, bo, out, blockIdx.x * 128, blockIdx.y * 64);
}

// ---------------------------------------------------------------------------
// MFMA flash attention. grid=(9, 8, 12), block 128 (2 waves, 32 q-rows each).
// S = Q.K^T via x2 split (qh,ql vs kh); softmax distributed over both waves;
// PV with P,V single bf16, V staged transposed.
// ---------------------------------------------------------------------------
__global__ __launch_bounds__(128) void attn_mfma_kernel(
    const float* __restrict__ Q, const float* __restrict__ K,
    const float* __restrict__ V, float* __restrict__ O)
{
    const int qt = blockIdx.x;                   // 0..8
    const int h  = blockIdx.y;                   // 0..7
    const int z  = blockIdx.z;                   // 0..11
    const int f  = (z < 8) ? (z + 4) : (z - 8);  // cross frames first (long blocks)

    const int t    = threadIdx.x;
    const int w    = t >> 6;
    const int lane = t & 63;
    const int quad = lane >> 4;
    const int ln   = lane & 15;

    __shared__ unsigned short KhS[64 * 104];  // [key][96+8 pad] bf16, cols 80..95 zeroed
    __shared__ unsigned short VtS[80 * 72];   // [d][64+8 pad] bf16 (transposed V)
    __shared__ float          Ssm[64 * 65];   // stride 65: bank = r+c -> conflict-free
    __shared__ unsigned short Pb[64 * 72];    // probs bf16, A-operand layout
    __shared__ float pm[128], ps[128], mrow[64], lrow[64], arow[64];

    const int kbase = (f < 4 ? f : (f < 8 ? 4 : 8)) * SEQ;
    const int nkt   = (f < 4) ? 9 : 36;
    const float scale = 0.11180339887498949f;   // 1/sqrt(80)

    // ---- Q fragments -> registers (A-layout), pre-scaled, hi/lo split ----
    bf16x8 qh[2][3], ql[2][3];
#pragma unroll
    for (int mi = 0; mi < 2; ++mi) {
        const int qrow = f * SEQ + qt * 64 + w * 32 + mi * 16 + ln;
        const float* qp = Q + (size_t)qrow * DIM + h * HD;
#pragma unroll
        for (int kc = 0; kc < 3; ++kc) {
            const int dbase = kc * 32 + quad * 8;
            union { unsigned short u[8]; bf16x8 v; } uh, ul;
            if (dbase < HD) {
                float4 a4 = *(const float4*)(qp + dbase);
                float4 b4 = *(const float4*)(qp + dbase + 4);
                float vv[8] = {a4.x, a4.y, a4.z, a4.w, b4.x, b4.y, b4.z, b4.w};
#pragma unroll
                for (int j = 0; j < 8; ++j) {
                    float x = vv[j] * scale;
                    unsigned short hh = f2bf(x);
                    uh.u[j] = hh;
                    ul.u[j] = f2bf(x - bf2f(hh));
                }
            } else {
#pragma unroll
                for (int j = 0; j < 8; ++j) { uh.u[j] = 0; ul.u[j] = 0; }
            }
            qh[mi][kc] = uh.v;
            ql[mi][kc] = ul.v;
        }
    }

    if (t < 64) { mrow[t] = -INFINITY; lrow[t] = 0.f; }

    f32x4 oacc[2][5];
#pragma unroll
    for (int mi = 0; mi < 2; ++mi)
#pragma unroll
        for (int nt = 0; nt < 5; ++nt)
#pragma unroll
            for (int e = 0; e < 4; ++e) oacc[mi][nt][e] = 0.f;

    for (int kt = 0; kt < nkt; ++kt) {
        __syncthreads();   // prev PV done with KhS/VtS/Pb
        // ---- stage K tile (bf16 hi): row t>>1, cols (t&1)*40 + [0,40) ----
        {
            const int r  = t >> 1;
            const int c0 = (t & 1) * 40;
            const float* kp = K + (size_t)(kbase + kt * 64 + r) * DIM + h * HD + c0;
#pragma unroll
            for (int i = 0; i < 40; i += 8) {
                float4 a4 = *(const float4*)(kp + i);
                float4 b4 = *(const float4*)(kp + i + 4);
                union { unsigned short u[8]; u16x8 v; } pk;
                pk.u[0] = f2bf(a4.x); pk.u[1] = f2bf(a4.y);
                pk.u[2] = f2bf(a4.z); pk.u[3] = f2bf(a4.w);
                pk.u[4] = f2bf(b4.x); pk.u[5] = f2bf(b4.y);
                pk.u[6] = f2bf(b4.z); pk.u[7] = f2bf(b4.w);
                *(u16x8*)&KhS[r * 104 + c0 + i] = pk.v;
            }
            if (t & 1) {   // zero pad cols 80..95 (read by kc=2, quads 2-3)
                union { unsigned short u[8]; u16x8 v; } zz;
#pragma unroll
                for (int j = 0; j < 8; ++j) zz.u[j] = 0;
                *(u16x8*)&KhS[r * 104 + 80] = zz.v;
                *(u16x8*)&KhS[r * 104 + 88] = zz.v;
            }
        }
        // ---- stage V transposed (bf16): units (jgrp 0..15, dgrp 0..9) ----
        for (int uu = t; uu < 160; uu += 128) {
            const int j0 = (uu & 15) * 4;
            const int d0 = (uu >> 4) * 8;
            unsigned short vb8[4][8];
#pragma unroll
            for (int jj = 0; jj < 4; ++jj) {
                const float* vp = V + (size_t)(kbase + kt * 64 + j0 + jj) * DIM + h * HD + d0;
                float4 a4 = *(const float4*)vp;
                float4 b4 = *(const float4*)(vp + 4);
                vb8[jj][0] = f2bf(a4.x); vb8[jj][1] = f2bf(a4.y);
                vb8[jj][2] = f2bf(a4.z); vb8[jj][3] = f2bf(a4.w);
                vb8[jj][4] = f2bf(b4.x); vb8[jj][5] = f2bf(b4.y);
                vb8[jj][6] = f2bf(b4.z); vb8[jj][7] = f2bf(b4.w);
            }
#pragma unroll
            for (int di = 0; di < 8; ++di) {
                union { unsigned short u[4]; u16x4 v; } pv;
                pv.u[0] = vb8[0][di]; pv.u[1] = vb8[1][di];
                pv.u[2] = vb8[2][di]; pv.u[3] = vb8[3][di];
                *(u16x4*)&VtS[(d0 + di) * 72 + j0] = pv.v;
            }
        }
        __syncthreads();

        // ---- S = Q.K^T (x2 split) ----
        f32x4 sacc[2][4];
#pragma unroll
        for (int mi = 0; mi < 2; ++mi)
#pragma unroll
            for (int nt = 0; nt < 4; ++nt)
#pragma unroll
                for (int e = 0; e < 4; ++e) sacc[mi][nt][e] = 0.f;

#pragma unroll
        for (int nt = 0; nt < 4; ++nt)
#pragma unroll
            for (int kc = 0; kc < 3; ++kc) {
                bf16x8 bh = *(const bf16x8*)&KhS[(nt * 16 + ln) * 104 + kc * 32 + quad * 8];
#pragma unroll
                for (int mi = 0; mi < 2; ++mi) {
                    sacc[mi][nt] = mfma16(qh[mi][kc], bh, sacc[mi][nt]);
                    sacc[mi][nt] = mfma16(ql[mi][kc], bh, sacc[mi][nt]);
                }
            }
#pragma unroll
        for (int mi = 0; mi < 2; ++mi)
#pragma unroll
            for (int nt = 0; nt < 4; ++nt)
#pragma unroll
                for (int r = 0; r < 4; ++r)
                    Ssm[(w * 32 + mi * 16 + quad * 4 + r) * 65 + nt * 16 + ln] = sacc[mi][nt][r];
        __syncthreads();

        // ---- softmax phase A: partial row max (wave w -> cols [32w,32w+32)) ----
        {
            const int r = t & 63, c0 = w * 32;
            float mx = -INFINITY;
#pragma unroll
            for (int c = 0; c < 32; ++c) mx = fmaxf(mx, Ssm[r * 65 + c0 + c]);
            pm[r * 2 + w] = mx;
        }
        __syncthreads();
        if (t < 64) {
            float mold = mrow[t];
            float mnew = fmaxf(mold, fmaxf(pm[2 * t], pm[2 * t + 1]));
            arow[t] = __expf(mold - mnew);
            mrow[t] = mnew;
        }
        __syncthreads();
        // ---- phase C: exp, write P (bf16), partial sums ----
        {
            const int r = t & 63, c0 = w * 32;
            const float m = mrow[r];
            float sum = 0.f;
#pragma unroll
            for (int c = 0; c < 32; c += 4) {
                float p0 = __expf(Ssm[r * 65 + c0 + c + 0] - m);
                float p1 = __expf(Ssm[r * 65 + c0 + c + 1] - m);
                float p2 = __expf(Ssm[r * 65 + c0 + c + 2] - m);
                float p3 = __expf(Ssm[r * 65 + c0 + c + 3] - m);
                sum += p0 + p1 + p2 + p3;
                union { unsigned short u[4]; u16x4 v; } pp;
                pp.u[0] = f2bf(p0); pp.u[1] = f2bf(p1);
                pp.u[2] = f2bf(p2); pp.u[3] = f2bf(p3);
                *(u16x4*)&Pb[r * 72 + c0 + c] = pp.v;
            }
            ps[r * 2 + w] = sum;
        }
        __syncthreads();
        if (t < 64) lrow[t] = lrow[t] * arow[t] + ps[2 * t] + ps[2 * t + 1];

        // ---- O rescale + PV ----
#pragma unroll
        for (int mi = 0; mi < 2; ++mi)
#pragma unroll
            for (int r = 0; r < 4; ++r) {
                float al = arow[w * 32 + mi * 16 + quad * 4 + r];
#pragma unroll
                for (int nt = 0; nt < 5; ++nt) oacc[mi][nt][r] *= al;
            }
#pragma unroll
        for (int kc = 0; kc < 2; ++kc) {
            bf16x8 pa0 = *(const bf16x8*)&Pb[(w * 32 + ln) * 72 + kc * 32 + quad * 8];
            bf16x8 pa1 = *(const bf16x8*)&Pb[(w * 32 + 16 + ln) * 72 + kc * 32 + quad * 8];
#pragma unroll
            for (int nt = 0; nt < 5; ++nt) {
                bf16x8 vh = *(const bf16x8*)&VtS[(nt * 16 + ln) * 72 + kc * 32 + quad * 8];
                oacc[0][nt] = mfma16(pa0, vh, oacc[0][nt]);
                oacc[1][nt] = mfma16(pa1, vh, oacc[1][nt]);
            }
        }
    }

    __syncthreads();
#pragma unroll
    for (int mi = 0; mi < 2; ++mi)
#pragma unroll
        for (int r = 0; r < 4; ++r) {
            const int rr   = w * 32 + mi * 16 + quad * 4 + r;
            const float li = 1.f / lrow[rr];
            const int orow = f * SEQ + qt * 64 + rr;
#pragma unroll
            for (int nt = 0; nt < 5; ++nt)
                O[(size_t)orow * DIM + h * HD + nt * 16 + ln] = oacc[mi][nt][r] * li;
        }
}

// ---------------------------------------------------------------------------
extern "C" void kernel_launch(void* const* d_in, const int* in_sizes, int n_in,
                              void* d_out, int out_size, void* d_ws, size_t ws_size,
                              hipStream_t stream)
{
    const float* x  = (const float*)d_in[0];
    const float* Wq = (const float*)d_in[1];
    const float* Wk = (const float*)d_in[2];
    const float* Wv = (const float*)d_in[3];
    const float* Wo = (const float*)d_in[4];
    const float* bo = (const float*)d_in[5];
    float* out = (float*)d_out;

    float* qb = (float*)d_ws;                    // [6912][640] fp32
    float* kb = qb + (size_t)M_TOT * DIM;
    float* vb = kb + (size_t)M_TOT * DIM;
    float* ab = vb + (size_t)M_TOT * DIM;        // attention output, pre-proj

    dim3 g1(M_TOT / 128, DIM / 64, 3);
    qkv_mfma_kernel<<<g1, 256, 0, stream>>>(x, Wq, Wk, Wv, qb, kb, vb);

    dim3 g2(SEQ / 64, HEADS, NB);
    attn_mfma_kernel<<<g2, 128, 0, stream>>>(qb, kb, vb, ab);

    dim3 g3(M_TOT / 128, DIM / 64);
    oproj_mfma_kernel<<<g3, 256, 0, stream>>>(ab, Wo, bo, out);
}

// Round 4
// 331.955 us; speedup vs baseline: 6.3660x; 1.1573x over previous
//
#include <hip/hip_runtime.h>
#include <hip/hip_bf16.h>

#define SEQ    576
#define DIM    640
#define HEADS  8
#define HD     80          // DIM / HEADS
#define NF     4
#define NB     12          // 3 * NF
#define M_TOT  (NB * SEQ)  // 6912
#define SCALE  0.11180339887498949f   // 1/sqrt(80)

typedef __attribute__((ext_vector_type(8))) short          bf16x8;
typedef __attribute__((ext_vector_type(4))) float          f32x4;
typedef __attribute__((ext_vector_type(8))) unsigned short u16x8;
typedef __attribute__((ext_vector_type(4))) unsigned short u16x4;

__device__ __forceinline__ unsigned short f2bf(float x) {
    unsigned u = __float_as_uint(x);
    u += 0x7fffu + ((u >> 16) & 1u);
    return (unsigned short)(u >> 16);
}
__device__ __forceinline__ float bf2f(unsigned short h) {
    return __uint_as_float((unsigned)h << 16);
}
__device__ __forceinline__ f32x4 mfma16(bf16x8 a, bf16x8 b, f32x4 c) {
    return __builtin_amdgcn_mfma_f32_16x16x32_bf16(a, b, c, 0, 0, 0);
}

// ---------------------------------------------------------------------------
// Split fp32 -> bf16 hi/lo (optionally scaled). grid=(1080, 5), block 256.
// z: 0=X, 1=Wq(*SCALE), 2=Wk, 3=Wv, 4=Wo. 16 elems/thread.
// ---------------------------------------------------------------------------
__global__ __launch_bounds__(256) void split_kernel(
    const float* __restrict__ X,  const float* __restrict__ Wq,
    const float* __restrict__ Wk, const float* __restrict__ Wv,
    const float* __restrict__ Wo,
    unsigned short* __restrict__ Xh,  unsigned short* __restrict__ Xl,
    unsigned short* __restrict__ Wqh, unsigned short* __restrict__ Wql,
    unsigned short* __restrict__ Wkh, unsigned short* __restrict__ Wkl,
    unsigned short* __restrict__ Wvh, unsigned short* __restrict__ Wvl,
    unsigned short* __restrict__ Woh, unsigned short* __restrict__ Wol)
{
    const int z = blockIdx.y;
    const float* src; unsigned short *dh, *dl; int n; float s = 1.0f;
    switch (z) {
        case 0:  src = X;  dh = Xh;  dl = Xl;  n = M_TOT * DIM; break;
        case 1:  src = Wq; dh = Wqh; dl = Wql; n = DIM * DIM; s = SCALE; break;
        case 2:  src = Wk; dh = Wkh; dl = Wkl; n = DIM * DIM; break;
        case 3:  src = Wv; dh = Wvh; dl = Wvl; n = DIM * DIM; break;
        default: src = Wo; dh = Woh; dl = Wol; n = DIM * DIM; break;
    }
    const int base = blockIdx.x * 4096 + threadIdx.x * 16;
    if (base >= n) return;
#pragma unroll
    for (int half = 0; half < 2; ++half) {
        const int b = base + half * 8;
        float4 a4 = *(const float4*)(src + b);
        float4 b4 = *(const float4*)(src + b + 4);
        float vv[8] = {a4.x, a4.y, a4.z, a4.w, b4.x, b4.y, b4.z, b4.w};
        union { unsigned short u[8]; u16x8 v; } ph, pl;
#pragma unroll
        for (int j = 0; j < 8; ++j) {
            float x = vv[j] * s;
            unsigned short hh = f2bf(x);
            ph.u[j] = hh;
            pl.u[j] = f2bf(x - bf2f(hh));
        }
        *(u16x8*)(dh + b) = ph.v;
        *(u16x8*)(dl + b) = pl.v;
    }
}

// ---------------------------------------------------------------------------
// QKV GEMM: acc = X * W^T (hi/lo x3 MFMA == fp32-accurate), epilogue per z:
//  z=0: Qh/Ql (split bf16, scale already folded into Wq)
//  z=1: Kb (bf16, [token][640])
//  z=2: Vt (bf16, transposed [640][M_TOT]) via LDS transpose
// block 256 (4 waves); tile 128(M) x 64(N); BK=32. grid=(54,10,3).
// ---------------------------------------------------------------------------
__global__ __launch_bounds__(256) void qkv_mfma_kernel(
    const unsigned short* __restrict__ Xh,  const unsigned short* __restrict__ Xl,
    const unsigned short* __restrict__ Wqh, const unsigned short* __restrict__ Wql,
    const unsigned short* __restrict__ Wkh, const unsigned short* __restrict__ Wkl,
    const unsigned short* __restrict__ Wvh, const unsigned short* __restrict__ Wvl,
    unsigned short* __restrict__ Qh, unsigned short* __restrict__ Ql,
    unsigned short* __restrict__ Kb, unsigned short* __restrict__ VtG)
{
    __shared__ unsigned short smem[15360];
    unsigned short* Ah = smem;            // 128*40
    unsigned short* Al = smem + 5120;
    unsigned short* Bh = smem + 10240;    // 64*40
    unsigned short* Bl = smem + 12800;

    const int z  = blockIdx.z;
    const unsigned short* WH = (z == 0) ? Wqh : ((z == 1) ? Wkh : Wvh);
    const unsigned short* WL = (z == 0) ? Wql : ((z == 1) ? Wkl : Wvl);
    const int m0 = blockIdx.x * 128;
    const int n0 = blockIdx.y * 64;

    const int t    = threadIdx.x;
    const int w    = t >> 6;
    const int lane = t & 63;
    const int quad = lane >> 4;
    const int ln   = lane & 15;

    f32x4 acc[2][4];
#pragma unroll
    for (int mi = 0; mi < 2; ++mi)
#pragma unroll
        for (int nt = 0; nt < 4; ++nt)
#pragma unroll
            for (int e = 0; e < 4; ++e) acc[mi][nt][e] = 0.f;

    for (int k0 = 0; k0 < DIM; k0 += 32) {
        __syncthreads();
        {
            const int r  = t >> 1;
            const int c0 = (t & 1) * 16;
            const size_t ga = (size_t)(m0 + r) * DIM + k0 + c0;
            *(u16x8*)&Ah[r * 40 + c0]     = *(const u16x8*)(Xh + ga);
            *(u16x8*)&Ah[r * 40 + c0 + 8] = *(const u16x8*)(Xh + ga + 8);
            *(u16x8*)&Al[r * 40 + c0]     = *(const u16x8*)(Xl + ga);
            *(u16x8*)&Al[r * 40 + c0 + 8] = *(const u16x8*)(Xl + ga + 8);
            const int rb = t >> 2;
            const int cb = (t & 3) * 8;
            const size_t gb = (size_t)(n0 + rb) * DIM + k0 + cb;
            *(u16x8*)&Bh[rb * 40 + cb] = *(const u16x8*)(WH + gb);
            *(u16x8*)&Bl[rb * 40 + cb] = *(const u16x8*)(WL + gb);
        }
        __syncthreads();

        bf16x8 ah[2], al[2];
#pragma unroll
        for (int mi = 0; mi < 2; ++mi) {
            const int off = (w * 32 + mi * 16 + ln) * 40 + quad * 8;
            ah[mi] = *(const bf16x8*)&Ah[off];
            al[mi] = *(const bf16x8*)&Al[off];
        }
#pragma unroll
        for (int nt = 0; nt < 4; ++nt) {
            const int off = (nt * 16 + ln) * 40 + quad * 8;
            bf16x8 bh = *(const bf16x8*)&Bh[off];
            bf16x8 bl = *(const bf16x8*)&Bl[off];
#pragma unroll
            for (int mi = 0; mi < 2; ++mi) {
                acc[mi][nt] = mfma16(ah[mi], bh, acc[mi][nt]);
                acc[mi][nt] = mfma16(ah[mi], bl, acc[mi][nt]);
                acc[mi][nt] = mfma16(al[mi], bh, acc[mi][nt]);
            }
        }
    }

    if (z == 0) {
#pragma unroll
        for (int mi = 0; mi < 2; ++mi)
#pragma unroll
            for (int r = 0; r < 4; ++r) {
                const size_t row = m0 + w * 32 + mi * 16 + quad * 4 + r;
#pragma unroll
                for (int nt = 0; nt < 4; ++nt) {
                    const int col = n0 + nt * 16 + ln;
                    float v = acc[mi][nt][r];
                    unsigned short hh = f2bf(v);
                    Qh[row * DIM + col] = hh;
                    Ql[row * DIM + col] = f2bf(v - bf2f(hh));
                }
            }
    } else if (z == 1) {
#pragma unroll
        for (int mi = 0; mi < 2; ++mi)
#pragma unroll
            for (int r = 0; r < 4; ++r) {
                const size_t row = m0 + w * 32 + mi * 16 + quad * 4 + r;
#pragma unroll
                for (int nt = 0; nt < 4; ++nt)
                    Kb[row * DIM + n0 + nt * 16 + ln] = f2bf(acc[mi][nt][r]);
            }
    } else {
        // transpose through LDS, then coalesced u16x8 stores of Vt rows
        __syncthreads();
        unsigned short* Vts = smem;   // 64 x 136 = 8704 shorts
#pragma unroll
        for (int mi = 0; mi < 2; ++mi)
#pragma unroll
            for (int nt = 0; nt < 4; ++nt)
#pragma unroll
                for (int r = 0; r < 4; ++r)
                    Vts[(nt * 16 + ln) * 136 + w * 32 + mi * 16 + quad * 4 + r] =
                        f2bf(acc[mi][nt][r]);
        __syncthreads();
        const int d = t & 63;
#pragma unroll
        for (int i = 0; i < 4; ++i) {
            const int c0 = (t >> 6) * 32 + i * 8;
            *(u16x8*)(VtG + (size_t)(n0 + d) * M_TOT + m0 + c0) =
                *(const u16x8*)&Vts[d * 136 + c0];
        }
    }
}

// ---------------------------------------------------------------------------
// MFMA flash attention v2. grid=(9, 8, 12), block 256 (4 waves x 16 q-rows).
// In-register online softmax (shfl within 16-lane groups); P transposed via
// wave-private LDS (no barrier); K pad pre-zeroed once; all inputs bf16.
// Output: hi/lo bf16 (Oh/Ol) for the split oproj GEMM.
// ---------------------------------------------------------------------------
__global__ __launch_bounds__(256) void attn_mfma_kernel(
    const unsigned short* __restrict__ Qh, const unsigned short* __restrict__ Ql,
    const unsigned short* __restrict__ Kb, const unsigned short* __restrict__ Vt,
    unsigned short* __restrict__ Oh, unsigned short* __restrict__ Ol)
{
    const int qt = blockIdx.x;                   // 0..8
    const int h  = blockIdx.y;                   // 0..7
    const int z  = blockIdx.z;                   // 0..11
    const int f  = (z < 8) ? (z + 4) : (z - 8);  // cross frames first

    const int t    = threadIdx.x;
    const int w    = t >> 6;
    const int lane = t & 63;
    const int quad = lane >> 4;
    const int ln   = lane & 15;

    __shared__ unsigned short KhS[64 * 104];  // [key][96+8], cols 80..95 zeroed once
    __shared__ unsigned short VtS[80 * 72];   // [d][64+8]
    __shared__ unsigned short Pb[4 * 16 * 72];// per-wave P, A-operand layout

    const int kbase = (f < 4 ? f : (f < 8 ? 4 : 8)) * SEQ;
    const int nkt   = (f < 4) ? 9 : 36;

    // zero K pad (cols 80..95), persists across iterations
    if (t < 64) {
        union { unsigned short u[8]; u16x8 v; } zz;
#pragma unroll
        for (int j = 0; j < 8; ++j) zz.u[j] = 0;
        *(u16x8*)&KhS[t * 104 + 80] = zz.v;
        *(u16x8*)&KhS[t * 104 + 88] = zz.v;
    }

    // ---- Q fragments (A-layout, pre-scaled hi/lo already in global) ----
    const int qrow = f * SEQ + qt * 64 + w * 16 + ln;
    const unsigned short* qph = Qh + (size_t)qrow * DIM + h * HD;
    const unsigned short* qpl = Ql + (size_t)qrow * DIM + h * HD;
    bf16x8 qfh[3], qfl[3];
#pragma unroll
    for (int kc = 0; kc < 3; ++kc) {
        const int dbase = kc * 32 + quad * 8;
        if (dbase < HD) {
            qfh[kc] = *(const bf16x8*)(qph + dbase);
            qfl[kc] = *(const bf16x8*)(qpl + dbase);
        } else {
            union { unsigned short u[8]; bf16x8 v; } zz;
#pragma unroll
            for (int j = 0; j < 8; ++j) zz.u[j] = 0;
            qfh[kc] = zz.v; qfl[kc] = zz.v;
        }
    }

    float m_[4], l_[4];
#pragma unroll
    for (int r = 0; r < 4; ++r) { m_[r] = -INFINITY; l_[r] = 0.f; }

    f32x4 oacc[5];
#pragma unroll
    for (int nt = 0; nt < 5; ++nt)
#pragma unroll
        for (int e = 0; e < 4; ++e) oacc[nt][e] = 0.f;

    unsigned short* PbW = &Pb[w * 16 * 72];

    for (int kt = 0; kt < nkt; ++kt) {
        __syncthreads();   // all waves done reading KhS/VtS of prev iter
        {   // stage K tile: 64 rows x 80 bf16 (pure copy)
            const int r  = t >> 2;
            const int c0 = (t & 3) * 20;
            const unsigned short* kp = Kb + (size_t)(kbase + kt * 64 + r) * DIM + h * HD + c0;
#pragma unroll
            for (int i = 0; i < 20; i += 4)
                *(u16x4*)&KhS[r * 104 + c0 + i] = *(const u16x4*)(kp + i);
        }
        {   // stage V^T tile: 80 d-rows x 64 keys (contiguous in global Vt)
#pragma unroll
            for (int u = t; u < 640; u += 256) {
                const int d = u >> 3, c = (u & 7) * 8;
                *(u16x8*)&VtS[d * 72 + c] =
                    *(const u16x8*)(Vt + (size_t)(h * HD + d) * M_TOT + kbase + kt * 64 + c);
            }
        }
        __syncthreads();

        // ---- S = Q.K^T (x2 split), 16 rows x 64 keys per wave ----
        f32x4 sacc[4];
#pragma unroll
        for (int nt = 0; nt < 4; ++nt)
#pragma unroll
            for (int e = 0; e < 4; ++e) sacc[nt][e] = 0.f;
#pragma unroll
        for (int nt = 0; nt < 4; ++nt)
#pragma unroll
            for (int kc = 0; kc < 3; ++kc) {
                bf16x8 kf = *(const bf16x8*)&KhS[(nt * 16 + ln) * 104 + kc * 32 + quad * 8];
                sacc[nt] = mfma16(qfh[kc], kf, sacc[nt]);
                sacc[nt] = mfma16(qfl[kc], kf, sacc[nt]);
            }

        // ---- in-register online softmax (rows quad*4+r, reduce over ln) ----
        float alpha[4];
#pragma unroll
        for (int r = 0; r < 4; ++r) {
            float mx = fmaxf(fmaxf(sacc[0][r], sacc[1][r]), fmaxf(sacc[2][r], sacc[3][r]));
            mx = fmaxf(mx, __shfl_xor(mx, 1));
            mx = fmaxf(mx, __shfl_xor(mx, 2));
            mx = fmaxf(mx, __shfl_xor(mx, 4));
            mx = fmaxf(mx, __shfl_xor(mx, 8));
            float mnew = fmaxf(m_[r], mx);
            alpha[r] = __expf(m_[r] - mnew);
            m_[r] = mnew;
        }
        float rs[4] = {0.f, 0.f, 0.f, 0.f};
#pragma unroll
        for (int nt = 0; nt < 4; ++nt)
#pragma unroll
            for (int r = 0; r < 4; ++r) {
                float p = __expf(sacc[nt][r] - m_[r]);
                rs[r] += p;
                PbW[(quad * 4 + r) * 72 + nt * 16 + ln] = f2bf(p);
            }
#pragma unroll
        for (int r = 0; r < 4; ++r) {
            float s = rs[r];
            s += __shfl_xor(s, 1);
            s += __shfl_xor(s, 2);
            s += __shfl_xor(s, 4);
            s += __shfl_xor(s, 8);
            l_[r] = l_[r] * alpha[r] + s;
#pragma unroll
            for (int nt = 0; nt < 5; ++nt) oacc[nt][r] *= alpha[r];
        }

        __threadfence_block();   // drain P writes (wave-private: no barrier)

        // ---- O += P.V  (P A-frag from LDS, V^T B-frag) ----
#pragma unroll
        for (int kc = 0; kc < 2; ++kc) {
            bf16x8 pf = *(const bf16x8*)&PbW[ln * 72 + kc * 32 + quad * 8];
#pragma unroll
            for (int nt = 0; nt < 5; ++nt) {
                bf16x8 vf = *(const bf16x8*)&VtS[(nt * 16 + ln) * 72 + kc * 32 + quad * 8];
                oacc[nt] = mfma16(pf, vf, oacc[nt]);
            }
        }
    }

    // ---- epilogue: normalize, split hi/lo, store ----
#pragma unroll
    for (int r = 0; r < 4; ++r) {
        const float inv = 1.f / l_[r];
        const size_t orow = f * SEQ + qt * 64 + w * 16 + quad * 4 + r;
#pragma unroll
        for (int nt = 0; nt < 5; ++nt) {
            float v = oacc[nt][r] * inv;
            unsigned short hh = f2bf(v);
            const size_t off = orow * DIM + h * HD + nt * 16 + ln;
            Oh[off] = hh;
            Ol[off] = f2bf(v - bf2f(hh));
        }
    }
}

// ---------------------------------------------------------------------------
// Output projection: out = O * Wo^T + bo (fp32 out). Same structure as QKV.
// ---------------------------------------------------------------------------
__global__ __launch_bounds__(256) void oproj_mfma_kernel(
    const unsigned short* __restrict__ Oh, const unsigned short* __restrict__ Ol,
    const unsigned short* __restrict__ Woh, const unsigned short* __restrict__ Wol,
    const float* __restrict__ bo, float* __restrict__ out)
{
    __shared__ unsigned short smem[15360];
    unsigned short* Ah = smem;
    unsigned short* Al = smem + 5120;
    unsigned short* Bh = smem + 10240;
    unsigned short* Bl = smem + 12800;

    const int m0 = blockIdx.x * 128;
    const int n0 = blockIdx.y * 64;

    const int t    = threadIdx.x;
    const int w    = t >> 6;
    const int lane = t & 63;
    const int quad = lane >> 4;
    const int ln   = lane & 15;

    f32x4 acc[2][4];
#pragma unroll
    for (int mi = 0; mi < 2; ++mi)
#pragma unroll
        for (int nt = 0; nt < 4; ++nt)
#pragma unroll
            for (int e = 0; e < 4; ++e) acc[mi][nt][e] = 0.f;

    for (int k0 = 0; k0 < DIM; k0 += 32) {
        __syncthreads();
        {
            const int r  = t >> 1;
            const int c0 = (t & 1) * 16;
            const size_t ga = (size_t)(m0 + r) * DIM + k0 + c0;
            *(u16x8*)&Ah[r * 40 + c0]     = *(const u16x8*)(Oh + ga);
            *(u16x8*)&Ah[r * 40 + c0 + 8] = *(const u16x8*)(Oh + ga + 8);
            *(u16x8*)&Al[r * 40 + c0]     = *(const u16x8*)(Ol + ga);
            *(u16x8*)&Al[r * 40 + c0 + 8] = *(const u16x8*)(Ol + ga + 8);
            const int rb = t >> 2;
            const int cb = (t & 3) * 8;
            const size_t gb = (size_t)(n0 + rb) * DIM + k0 + cb;
            *(u16x8*)&Bh[rb * 40 + cb] = *(const u16x8*)(Woh + gb);
            *(u16x8*)&Bl[rb * 40 + cb] = *(const u16x8*)(Wol + gb);
        }
        __syncthreads();

        bf16x8 ah[2], al[2];
#pragma unroll
        for (int mi = 0; mi < 2; ++mi) {
            const int off = (w * 32 + mi * 16 + ln) * 40 + quad * 8;
            ah[mi] = *(const bf16x8*)&Ah[off];
            al[mi] = *(const bf16x8*)&Al[off];
        }
#pragma unroll
        for (int nt = 0; nt < 4; ++nt) {
            const int off = (nt * 16 + ln) * 40 + quad * 8;
            bf16x8 bh = *(const bf16x8*)&Bh[off];
            bf16x8 bl = *(const bf16x8*)&Bl[off];
#pragma unroll
            for (int mi = 0; mi < 2; ++mi) {
                acc[mi][nt] = mfma16(ah[mi], bh, acc[mi][nt]);
                acc[mi][nt] = mfma16(ah[mi], bl, acc[mi][nt]);
                acc[mi][nt] = mfma16(al[mi], bh, acc[mi][nt]);
            }
        }
    }

#pragma unroll
    for (int mi = 0; mi < 2; ++mi)
#pragma unroll
        for (int r = 0; r < 4; ++r) {
            const size_t row = m0 + w * 32 + mi * 16 + quad * 4 + r;
#pragma unroll
            for (int nt = 0; nt < 4; ++nt) {
                const int col = n0 + nt * 16 + ln;
                out[row * DIM + col] = acc[mi][nt][r] + bo[col];
            }
        }
}

// ---------------------------------------------------------------------------
extern "C" void kernel_launch(void* const* d_in, const int* in_sizes, int n_in,
                              void* d_out, int out_size, void* d_ws, size_t ws_size,
                              hipStream_t stream)
{
    const float* x  = (const float*)d_in[0];
    const float* Wq = (const float*)d_in[1];
    const float* Wk = (const float*)d_in[2];
    const float* Wv = (const float*)d_in[3];
    const float* Wo = (const float*)d_in[4];
    const float* bo = (const float*)d_in[5];
    float* out = (float*)d_out;

    const size_t NX = (size_t)M_TOT * DIM;   // 4,423,680
    const size_t NW = (size_t)DIM * DIM;     // 409,600
    unsigned short* p = (unsigned short*)d_ws;
    unsigned short* Xh  = p;            p += NX;
    unsigned short* Xl  = p;            p += NX;
    unsigned short* Wqh = p;            p += NW;
    unsigned short* Wql = p;            p += NW;
    unsigned short* Wkh = p;            p += NW;
    unsigned short* Wkl = p;            p += NW;
    unsigned short* Wvh = p;            p += NW;
    unsigned short* Wvl = p;            p += NW;
    unsigned short* Woh = p;            p += NW;
    unsigned short* Wol = p;            p += NW;
    unsigned short* Qhb = p;            p += NX;
    unsigned short* Qlb = p;            p += NX;
    unsigned short* Kbb = p;            p += NX;
    unsigned short* Vtb = p;            p += NX;
    unsigned short* Ohb = Xh;           // alias: X splits dead after QKV GEMM
    unsigned short* Olb = Xl;

    dim3 g0((M_TOT * DIM) / 4096, 5);
    split_kernel<<<g0, 256, 0, stream>>>(x, Wq, Wk, Wv, Wo,
        Xh, Xl, Wqh, Wql, Wkh, Wkl, Wvh, Wvl, Woh, Wol);

    dim3 g1(M_TOT / 128, DIM / 64, 3);
    qkv_mfma_kernel<<<g1, 256, 0, stream>>>(Xh, Xl, Wqh, Wql, Wkh, Wkl, Wvh, Wvl,
                                            Qhb, Qlb, Kbb, Vtb);

    dim3 g2(SEQ / 64, HEADS, NB);
    attn_mfma_kernel<<<g2, 256, 0, stream>>>(Qhb, Qlb, Kbb, Vtb, Ohb, Olb);

    dim3 g3(M_TOT / 128, DIM / 64);
    oproj_mfma_kernel<<<g3, 256, 0, stream>>>(Ohb, Olb, Woh, Wol, bo, out);
}